// Round 3
// baseline (499.041 us; speedup 1.0000x reference)
//
#include <hip/hip_runtime.h>
#include <cstdint>
#include <cstddef>

#define F_IN 256
#define F_OUT 128
#define NEG_SLOPE 0.2f

// ---------------- GEMM: h = x @ W (fp32) + fused logits ----------------
// BM=64 rows/block, BN=128 (full F_OUT), BK=32, 128 threads, 8x8 per thread.
// Double-buffered LDS; W staged via global_load_lds (16B), x via regs.
#define BM 64
#define BK 32
#define NT (F_IN / BK)   // 8 K-tiles

__device__ __forceinline__ void glds16(const float* g, float* l) {
  __builtin_amdgcn_global_load_lds((const __attribute__((address_space(1))) void*)g,
                                   (__attribute__((address_space(3))) void*)l, 16, 0, 0);
}

__global__ __launch_bounds__(128) void gemm_kernel(const float* __restrict__ x,
                                                   const float* __restrict__ W,
                                                   const float* __restrict__ att_src,
                                                   const float* __restrict__ att_dst,
                                                   float* __restrict__ h,
                                                   float* __restrict__ a_src,
                                                   float* __restrict__ a_dst, int N) {
  __shared__ float xs[2][BK][BM + 4];   // [buf][k][m], stride 68 floats
  __shared__ float ws[2][BK][F_OUT];    // [buf][k][n], contiguous (glds dest)
  const int tid  = threadIdx.x;
  const int tx   = tid & 15;            // col group: cols tx*4.. and 64+tx*4..
  const int ty   = tid >> 4;            // row group: rows ty*8 .. ty*8+7
  const int lane = tid & 63;
  const int wv   = tid >> 6;            // wave id 0..1
  const int m0   = blockIdx.x * BM;

  float acc[8][8];
#pragma unroll
  for (int r = 0; r < 8; ++r)
#pragma unroll
    for (int c = 0; c < 8; ++c) acc[r][c] = 0.f;

  float4 xv[4];

  // ---- helpers ----
  auto load_x = [&](int t) {
#pragma unroll
    for (int it = 0; it < 4; ++it) {
      int idx = tid + it * 128;        // 0..511
      int row = idx >> 3;              // 0..63
      int c4  = (idx & 7) * 4;         // 0..28
      int gm  = m0 + row;
      xv[it] = (gm < N) ? *(const float4*)(x + (size_t)gm * F_IN + t * BK + c4)
                        : make_float4(0.f, 0.f, 0.f, 0.f);
    }
  };
  auto store_x = [&](int b) {
#pragma unroll
    for (int it = 0; it < 4; ++it) {
      int idx = tid + it * 128;
      int row = idx >> 3;
      int c4  = (idx & 7) * 4;
      xs[b][c4 + 0][row] = xv[it].x;
      xs[b][c4 + 1][row] = xv[it].y;
      xs[b][c4 + 2][row] = xv[it].z;
      xs[b][c4 + 3][row] = xv[it].w;
    }
  };
  auto glds_w = [&](int t, int b) {
    const float* gbase = W + (size_t)t * BK * F_OUT;   // contiguous 16KB tile
    float* lbase = &ws[b][0][0];
#pragma unroll
    for (int i = 0; i < 8; ++i) {
      int chunk = i * 2 + wv;                          // 0..15, 1KB each
      glds16(gbase + chunk * 256 + lane * 4, lbase + chunk * 256);
    }
  };

  // ---- prologue ----
  glds_w(0, 0);
  load_x(0);
  store_x(0);
  __syncthreads();

  // ---- main loop ----
#pragma unroll 1
  for (int t = 0; t < NT; ++t) {
    int b = t & 1;
    if (t + 1 < NT) {
      glds_w(t + 1, b ^ 1);
      load_x(t + 1);
    }
#pragma unroll
    for (int kk = 0; kk < BK; ++kk) {
      float4 xa  = *(const float4*)&xs[b][kk][ty * 8];
      float4 xb4 = *(const float4*)&xs[b][kk][ty * 8 + 4];
      float4 wa  = *(const float4*)&ws[b][kk][tx * 4];
      float4 wb4 = *(const float4*)&ws[b][kk][64 + tx * 4];
      float xr[8] = {xa.x, xa.y, xa.z, xa.w, xb4.x, xb4.y, xb4.z, xb4.w};
      float wc[8] = {wa.x, wa.y, wa.z, wa.w, wb4.x, wb4.y, wb4.z, wb4.w};
#pragma unroll
      for (int r = 0; r < 8; ++r)
#pragma unroll
        for (int c = 0; c < 8; ++c)
          acc[r][c] += xr[r] * wc[c];
    }
    if (t + 1 < NT) store_x(b ^ 1);
    __syncthreads();
  }

  // ---- epilogue: write h + fused logits ----
  float as8[8], ad8[8];
#pragma unroll
  for (int c = 0; c < 4; ++c) {
    as8[c]     = att_src[tx * 4 + c];
    as8[4 + c] = att_src[64 + tx * 4 + c];
    ad8[c]     = att_dst[tx * 4 + c];
    ad8[4 + c] = att_dst[64 + tx * 4 + c];
  }
#pragma unroll
  for (int q = 0; q < 8; ++q) {
    int gm = m0 + ty * 8 + q;
    float ps = 0.f, pd = 0.f;
#pragma unroll
    for (int c = 0; c < 8; ++c) {
      ps += acc[q][c] * as8[c];
      pd += acc[q][c] * ad8[c];
    }
#pragma unroll
    for (int off = 8; off >= 1; off >>= 1) {
      ps += __shfl_down(ps, off, 16);
      pd += __shfl_down(pd, off, 16);
    }
    if (gm < N) {
      float4 va = {acc[q][0], acc[q][1], acc[q][2], acc[q][3]};
      float4 vb = {acc[q][4], acc[q][5], acc[q][6], acc[q][7]};
      *(float4*)&h[(size_t)gm * F_OUT + tx * 4]      = va;
      *(float4*)&h[(size_t)gm * F_OUT + 64 + tx * 4] = vb;
      if (tx == 0) { a_src[gm] = ps; a_dst[gm] = pd; }
    }
  }
}

// ---------------- CSR build ----------------
__global__ void deg_init_kernel(int* __restrict__ deg, int N) {
  int i = blockIdx.x * blockDim.x + threadIdx.x;
  if (i < N) deg[i] = 1;  // self loop
}

__global__ void deg_count_kernel(const int* __restrict__ ei, int* __restrict__ deg, int E) {
  int e = blockIdx.x * blockDim.x + threadIdx.x;
  if (e < E) atomicAdd(&deg[ei[E + e]], 1);  // row 1 = dst
}

#define SCAN_CHUNK 2048  // 256 threads x 8 elements

__global__ __launch_bounds__(256) void scan_chunk_kernel(const int* __restrict__ deg,
                                                         int* __restrict__ rowptr,
                                                         int* __restrict__ chunksum, int N) {
  __shared__ int wsum[4];
  const int tid = threadIdx.x, lane = tid & 63, wid = tid >> 6;
  const int base = blockIdx.x * SCAN_CHUNK + tid * 8;
  int v[8];
  int s = 0;
#pragma unroll
  for (int q = 0; q < 8; ++q) {
    int i = base + q;
    v[q] = (i < N) ? deg[i] : 0;
    s += v[q];
  }
  int incl = s;
#pragma unroll
  for (int off = 1; off < 64; off <<= 1) {
    int t = __shfl_up(incl, off, 64);
    if (lane >= off) incl += t;
  }
  if (lane == 63) wsum[wid] = incl;
  __syncthreads();
  int woff = 0;
#pragma unroll
  for (int w = 0; w < 4; ++w)
    if (w < wid) woff += wsum[w];
  int run = woff + incl - s;
#pragma unroll
  for (int q = 0; q < 8; ++q) {
    run += v[q];
    int i = base + q;
    if (i < N) rowptr[i + 1] = run;
  }
  if (tid == 0) chunksum[blockIdx.x] = wsum[0] + wsum[1] + wsum[2] + wsum[3];
}

__global__ void scan_offsets_kernel(const int* __restrict__ chunksum,
                                    int* __restrict__ chunkoff, int NB) {
  if (threadIdx.x == 0 && blockIdx.x == 0) {
    int run = 0;
    for (int b = 0; b < NB; ++b) { chunkoff[b] = run; run += chunksum[b]; }
  }
}

__global__ void scan_fixup_kernel(const int* __restrict__ deg, int* __restrict__ rowptr,
                                  int* __restrict__ cursor, const int* __restrict__ chunkoff,
                                  int N) {
  int i = blockIdx.x * blockDim.x + threadIdx.x;
  if (i == 0) rowptr[0] = 0;
  if (i < N) {
    int r = rowptr[i + 1] + chunkoff[i / SCAN_CHUNK];
    rowptr[i + 1] = r;
    cursor[i] = r - deg[i];
  }
}

// scatter + fused edge logit (a_src/a_dst are 200KB each -> L2-resident gathers)
__global__ void scatter_kernel(const int* __restrict__ ei, int* __restrict__ cursor,
                               const float* __restrict__ a_src, const float* __restrict__ a_dst,
                               int* __restrict__ csr_src, float* __restrict__ ew,
                               int E, int N) {
  int idx = blockIdx.x * blockDim.x + threadIdx.x;
  if (idx >= E + N) return;
  int s, d;
  if (idx < E) { s = ei[idx]; d = ei[E + idx]; }
  else { s = d = idx - E; }
  float e = a_src[s] + a_dst[d];
  e = (e > 0.f) ? e : NEG_SLOPE * e;
  int p = atomicAdd(&cursor[d], 1);
  csr_src[p] = s;
  ew[p] = e;
}

// ---------------- softmax stats: 16 lanes per node, contiguous ew ----------------
__global__ __launch_bounds__(256) void stats_kernel(const int* __restrict__ rowptr,
                                                    float* __restrict__ ew,
                                                    float* __restrict__ inv, int N) {
  int node = ((blockIdx.x * 256 + threadIdx.x) >> 4);
  int sub = threadIdx.x & 15;
  if (node >= N) return;
  int beg = rowptr[node], end = rowptr[node + 1];
  float m = -INFINITY;
  for (int j = beg + sub; j < end; j += 16) m = fmaxf(m, ew[j]);
#pragma unroll
  for (int off = 8; off >= 1; off >>= 1) m = fmaxf(m, __shfl_xor(m, off, 16));
  float s = 0.f;
  for (int j = beg + sub; j < end; j += 16) {
    float p = __expf(ew[j] - m);
    ew[j] = p;
    s += p;
  }
#pragma unroll
  for (int off = 8; off >= 1; off >>= 1) s += __shfl_xor(s, off, 16);
  if (sub == 0) inv[node] = 1.f / (s + 1e-16f);
}

// ---------------- weighted aggregate: 128 threads per node, x4 unrolled gathers ----------------
__global__ __launch_bounds__(256) void aggregate_kernel(const float* __restrict__ h,
                                                        const float* __restrict__ ew,
                                                        const float* __restrict__ inv,
                                                        const int* __restrict__ rowptr,
                                                        const int* __restrict__ csr_src,
                                                        const float* __restrict__ bias,
                                                        float* __restrict__ out, int N) {
  int node = blockIdx.x * 2 + (threadIdx.x >> 7);
  if (node >= N) return;
  int f = threadIdx.x & 127;
  int beg = rowptr[node], end = rowptr[node + 1];
  float acc = 0.f;
  int j = beg;
  for (; j + 4 <= end; j += 4) {
    int s0 = csr_src[j], s1 = csr_src[j + 1], s2 = csr_src[j + 2], s3 = csr_src[j + 3];
    float w0 = ew[j], w1 = ew[j + 1], w2 = ew[j + 2], w3 = ew[j + 3];
    float h0 = h[(size_t)s0 * F_OUT + f];
    float h1 = h[(size_t)s1 * F_OUT + f];
    float h2 = h[(size_t)s2 * F_OUT + f];
    float h3 = h[(size_t)s3 * F_OUT + f];
    acc += w0 * h0 + w1 * h1 + w2 * h2 + w3 * h3;
  }
  for (; j < end; ++j) acc += ew[j] * h[(size_t)csr_src[j] * F_OUT + f];
  out[(size_t)node * F_OUT + f] = acc * inv[node] + bias[f];
}

// ---------------- launch ----------------
extern "C" void kernel_launch(void* const* d_in, const int* in_sizes, int n_in,
                              void* d_out, int out_size, void* d_ws, size_t ws_size,
                              hipStream_t stream) {
  const float* x     = (const float*)d_in[0];
  const int*   ei    = (const int*)d_in[1];
  const float* W     = (const float*)d_in[2];
  const float* att_s = (const float*)d_in[3];
  const float* att_d = (const float*)d_in[4];
  const float* bias  = (const float*)d_in[5];
  float* out = (float*)d_out;

  const int N = in_sizes[0] / F_IN;
  const int E = in_sizes[1] / 2;
  const int NB = (N + SCAN_CHUNK - 1) / SCAN_CHUNK;

  char* p = (char*)d_ws;
  float* h     = (float*)p;  p += (size_t)N * F_OUT * sizeof(float);
  float* a_src = (float*)p;  p += (size_t)N * sizeof(float);
  float* a_dst = (float*)p;  p += (size_t)N * sizeof(float);
  float* inv   = (float*)p;  p += (size_t)N * sizeof(float);
  int*   deg   = (int*)p;    p += (size_t)N * sizeof(int);
  int*   rowp  = (int*)p;    p += (size_t)(N + 1) * sizeof(int);
  int*   curs  = (int*)p;    p += (size_t)N * sizeof(int);
  int*   csum  = (int*)p;    p += (size_t)NB * sizeof(int);
  int*   coff  = (int*)p;    p += (size_t)NB * sizeof(int);
  int*   csr   = (int*)p;    p += (size_t)(E + N) * sizeof(int);
  float* ew    = (float*)p;  p += (size_t)(E + N) * sizeof(float);

  gemm_kernel<<<(N + BM - 1) / BM, 128, 0, stream>>>(x, W, att_s, att_d, h, a_src, a_dst, N);
  deg_init_kernel<<<(N + 255) / 256, 256, 0, stream>>>(deg, N);
  deg_count_kernel<<<(E + 255) / 256, 256, 0, stream>>>(ei, deg, E);
  scan_chunk_kernel<<<NB, 256, 0, stream>>>(deg, rowp, csum, N);
  scan_offsets_kernel<<<1, 64, 0, stream>>>(csum, coff, NB);
  scan_fixup_kernel<<<(N + 255) / 256, 256, 0, stream>>>(deg, rowp, curs, coff, N);
  scatter_kernel<<<(E + N + 255) / 256, 256, 0, stream>>>(ei, curs, a_src, a_dst, csr, ew, E, N);
  stats_kernel<<<((size_t)N * 16 + 255) / 256, 256, 0, stream>>>(rowp, ew, inv, N);
  aggregate_kernel<<<(N + 1) / 2, 256, 0, stream>>>(h, ew, inv, rowp, csr, bias, out, N);
}

// Round 4
// 288.215 us; speedup vs baseline: 1.7315x; 1.7315x over previous
//
#include <hip/hip_runtime.h>
#include <cstdint>
#include <cstddef>

#define F_IN 256
#define F_OUT 128
#define NEG_SLOPE 0.2f

typedef short short8 __attribute__((ext_vector_type(8)));
typedef float f32x4 __attribute__((ext_vector_type(4)));

__device__ __forceinline__ unsigned short f2bf_rne(float f) {
  unsigned u = __float_as_uint(f);
  u += 0x7FFFu + ((u >> 16) & 1u);   // round-to-nearest-even
  return (unsigned short)(u >> 16);
}

// ---------------- cast+transpose W -> Wt[n][k] bf16 ----------------
__global__ __launch_bounds__(256) void castW_kernel(const float* __restrict__ W,
                                                    unsigned short* __restrict__ Wt) {
  int idx = blockIdx.x * 256 + threadIdx.x;   // 32768 = 256*128
  int n = idx & 127, k = idx >> 7;
  Wt[(size_t)n * F_IN + k] = f2bf_rne(W[(size_t)k * F_OUT + n]);
}

// ---------------- GEMM: h = x @ W via bf16 MFMA + fused logits ----------------
// BM=64 (4 waves x 16 rows), BN=128 (full F_OUT), K=256 in 4 tiles of 64.
// Wt tile staged in LDS (padded rows); A-frags loaded direct global->reg + cvt.
#define WT_STRIDE 72   // 64 + 8 pad (bf16 elems); row = 144 B, 16B-aligned

__global__ __launch_bounds__(256, 4) void gemm_kernel(const float* __restrict__ x,
                                                      const unsigned short* __restrict__ Wt,
                                                      const float* __restrict__ att_src,
                                                      const float* __restrict__ att_dst,
                                                      float* __restrict__ h,
                                                      float* __restrict__ a_src,
                                                      float* __restrict__ a_dst, int N) {
  __shared__ __attribute__((aligned(16))) unsigned short wt_l[128 * WT_STRIDE];
  const int tid  = threadIdx.x;
  const int lane = tid & 63;
  const int wv   = tid >> 6;        // wave = m-tile 0..3
  const int q    = lane >> 4;       // quad 0..3
  const int l16  = lane & 15;
  const int m0   = blockIdx.x * 64;
  const int m    = m0 + wv * 16 + l16;      // A row this lane loads
  const int mc   = (m < N) ? m : (N - 1);   // clamped (results discarded)

  f32x4 acc[8];
#pragma unroll
  for (int i = 0; i < 8; ++i) acc[i] = (f32x4)(0.f);

  const int srow  = tid >> 1;   // 0..127 staging row
  const int shalf = tid & 1;    // k-half 0..1

#pragma unroll 1
  for (int t = 0; t < 4; ++t) {
    // ---- stage Wt tile k in [t*64, t*64+64) ----
    {
      const unsigned short* g = Wt + (size_t)srow * F_IN + t * 64 + shalf * 32;
      unsigned short* l = wt_l + srow * WT_STRIDE + shalf * 32;
#pragma unroll
      for (int j = 0; j < 4; ++j)
        *(uint4*)(l + j * 8) = *(const uint4*)(g + j * 8);
    }
    __syncthreads();

#pragma unroll
    for (int s = 0; s < 2; ++s) {
      const int kg = t * 64 + s * 32 + q * 8;
      f32x4 a0 = *(const f32x4*)(x + (size_t)mc * F_IN + kg);
      f32x4 a1 = *(const f32x4*)(x + (size_t)mc * F_IN + kg + 4);
      short8 av;
      av[0] = (short)f2bf_rne(a0[0]); av[1] = (short)f2bf_rne(a0[1]);
      av[2] = (short)f2bf_rne(a0[2]); av[3] = (short)f2bf_rne(a0[3]);
      av[4] = (short)f2bf_rne(a1[0]); av[5] = (short)f2bf_rne(a1[1]);
      av[6] = (short)f2bf_rne(a1[2]); av[7] = (short)f2bf_rne(a1[3]);
#pragma unroll
      for (int nt = 0; nt < 8; ++nt) {
        short8 bv = *(const short8*)(wt_l + (nt * 16 + l16) * WT_STRIDE + s * 32 + q * 8);
        acc[nt] = __builtin_amdgcn_mfma_f32_16x16x32_bf16(av, bv, acc[nt], 0, 0, 0);
      }
    }
    __syncthreads();
  }

  // ---- epilogue: h writes + fused logits ----
  // C/D layout: col = nt*16 + l16, row (within m-tile) = q*4 + reg
  float as_c[8], ad_c[8];
#pragma unroll
  for (int nt = 0; nt < 8; ++nt) {
    as_c[nt] = att_src[nt * 16 + l16];
    ad_c[nt] = att_dst[nt * 16 + l16];
  }
  float ps[4] = {0.f, 0.f, 0.f, 0.f}, pd[4] = {0.f, 0.f, 0.f, 0.f};
#pragma unroll
  for (int nt = 0; nt < 8; ++nt)
#pragma unroll
    for (int r = 0; r < 4; ++r) {
      ps[r] += acc[nt][r] * as_c[nt];
      pd[r] += acc[nt][r] * ad_c[nt];
    }
#pragma unroll
  for (int r = 0; r < 4; ++r) {
    int gm = m0 + wv * 16 + q * 4 + r;
    if (gm < N) {
#pragma unroll
      for (int nt = 0; nt < 8; ++nt)
        h[(size_t)gm * F_OUT + nt * 16 + l16] = acc[nt][r];
    }
  }
#pragma unroll
  for (int r = 0; r < 4; ++r) {
#pragma unroll
    for (int off = 1; off <= 8; off <<= 1) {
      ps[r] += __shfl_xor(ps[r], off, 64);
      pd[r] += __shfl_xor(pd[r], off, 64);
    }
  }
  if (l16 == 0) {
#pragma unroll
    for (int r = 0; r < 4; ++r) {
      int gm = m0 + wv * 16 + q * 4 + r;
      if (gm < N) { a_src[gm] = ps[r]; a_dst[gm] = pd[r]; }
    }
  }
}

// ---------------- CSR build ----------------
__global__ void deg_init_kernel(int* __restrict__ deg, int N) {
  int i = blockIdx.x * blockDim.x + threadIdx.x;
  if (i < N) deg[i] = 1;  // self loop
}

__global__ void deg_count_kernel(const int* __restrict__ ei, int* __restrict__ deg, int E) {
  int e = blockIdx.x * blockDim.x + threadIdx.x;
  if (e < E) atomicAdd(&deg[ei[E + e]], 1);  // row 1 = dst
}

#define SCAN_CHUNK 2048  // 256 threads x 8 elements

__global__ __launch_bounds__(256) void scan_chunk_kernel(const int* __restrict__ deg,
                                                         int* __restrict__ rowptr,
                                                         int* __restrict__ chunksum, int N) {
  __shared__ int wsum[4];
  const int tid = threadIdx.x, lane = tid & 63, wid = tid >> 6;
  const int base = blockIdx.x * SCAN_CHUNK + tid * 8;
  int v[8];
  int s = 0;
#pragma unroll
  for (int q = 0; q < 8; ++q) {
    int i = base + q;
    v[q] = (i < N) ? deg[i] : 0;
    s += v[q];
  }
  int incl = s;
#pragma unroll
  for (int off = 1; off < 64; off <<= 1) {
    int t = __shfl_up(incl, off, 64);
    if (lane >= off) incl += t;
  }
  if (lane == 63) wsum[wid] = incl;
  __syncthreads();
  int woff = 0;
#pragma unroll
  for (int w = 0; w < 4; ++w)
    if (w < wid) woff += wsum[w];
  int run = woff + incl - s;
#pragma unroll
  for (int q = 0; q < 8; ++q) {
    run += v[q];
    int i = base + q;
    if (i < N) rowptr[i + 1] = run;
  }
  if (tid == 0) chunksum[blockIdx.x] = wsum[0] + wsum[1] + wsum[2] + wsum[3];
}

__global__ void scan_offsets_kernel(const int* __restrict__ chunksum,
                                    int* __restrict__ chunkoff, int NB) {
  if (threadIdx.x == 0 && blockIdx.x == 0) {
    int run = 0;
    for (int b = 0; b < NB; ++b) { chunkoff[b] = run; run += chunksum[b]; }
  }
}

__global__ void scan_fixup_kernel(const int* __restrict__ deg, int* __restrict__ rowptr,
                                  int* __restrict__ cursor, const int* __restrict__ chunkoff,
                                  int N) {
  int i = blockIdx.x * blockDim.x + threadIdx.x;
  if (i == 0) rowptr[0] = 0;
  if (i < N) {
    int r = rowptr[i + 1] + chunkoff[i / SCAN_CHUNK];
    rowptr[i + 1] = r;
    cursor[i] = r - deg[i];
  }
}

// scatter + fused edge logit (a_src/a_dst are 200KB each -> L2-resident gathers)
__global__ void scatter_kernel(const int* __restrict__ ei, int* __restrict__ cursor,
                               const float* __restrict__ a_src, const float* __restrict__ a_dst,
                               int* __restrict__ csr_src, float* __restrict__ ew,
                               int E, int N) {
  int idx = blockIdx.x * blockDim.x + threadIdx.x;
  if (idx >= E + N) return;
  int s, d;
  if (idx < E) { s = ei[idx]; d = ei[E + idx]; }
  else { s = d = idx - E; }
  float e = a_src[s] + a_dst[d];
  e = (e > 0.f) ? e : NEG_SLOPE * e;
  int p = atomicAdd(&cursor[d], 1);
  csr_src[p] = s;
  ew[p] = e;
}

// ---------------- softmax stats: 16 lanes per node, contiguous ew ----------------
__global__ __launch_bounds__(256) void stats_kernel(const int* __restrict__ rowptr,
                                                    float* __restrict__ ew,
                                                    float* __restrict__ inv, int N) {
  int node = ((blockIdx.x * 256 + threadIdx.x) >> 4);
  int sub = threadIdx.x & 15;
  if (node >= N) return;
  int beg = rowptr[node], end = rowptr[node + 1];
  float m = -INFINITY;
  for (int j = beg + sub; j < end; j += 16) m = fmaxf(m, ew[j]);
#pragma unroll
  for (int off = 8; off >= 1; off >>= 1) m = fmaxf(m, __shfl_xor(m, off, 16));
  float s = 0.f;
  for (int j = beg + sub; j < end; j += 16) {
    float p = __expf(ew[j] - m);
    ew[j] = p;
    s += p;
  }
#pragma unroll
  for (int off = 8; off >= 1; off >>= 1) s += __shfl_xor(s, off, 16);
  if (sub == 0) inv[node] = 1.f / (s + 1e-16f);
}

// ---------------- weighted aggregate: 128 threads per node, x4 unrolled gathers ----------------
__global__ __launch_bounds__(256) void aggregate_kernel(const float* __restrict__ h,
                                                        const float* __restrict__ ew,
                                                        const float* __restrict__ inv,
                                                        const int* __restrict__ rowptr,
                                                        const int* __restrict__ csr_src,
                                                        const float* __restrict__ bias,
                                                        float* __restrict__ out, int N) {
  int node = blockIdx.x * 2 + (threadIdx.x >> 7);
  if (node >= N) return;
  int f = threadIdx.x & 127;
  int beg = rowptr[node], end = rowptr[node + 1];
  float acc = 0.f;
  int j = beg;
  for (; j + 4 <= end; j += 4) {
    int s0 = csr_src[j], s1 = csr_src[j + 1], s2 = csr_src[j + 2], s3 = csr_src[j + 3];
    float w0 = ew[j], w1 = ew[j + 1], w2 = ew[j + 2], w3 = ew[j + 3];
    float h0 = h[(size_t)s0 * F_OUT + f];
    float h1 = h[(size_t)s1 * F_OUT + f];
    float h2 = h[(size_t)s2 * F_OUT + f];
    float h3 = h[(size_t)s3 * F_OUT + f];
    acc += w0 * h0 + w1 * h1 + w2 * h2 + w3 * h3;
  }
  for (; j < end; ++j) acc += ew[j] * h[(size_t)csr_src[j] * F_OUT + f];
  out[(size_t)node * F_OUT + f] = acc * inv[node] + bias[f];
}

// ---------------- launch ----------------
extern "C" void kernel_launch(void* const* d_in, const int* in_sizes, int n_in,
                              void* d_out, int out_size, void* d_ws, size_t ws_size,
                              hipStream_t stream) {
  const float* x     = (const float*)d_in[0];
  const int*   ei    = (const int*)d_in[1];
  const float* W     = (const float*)d_in[2];
  const float* att_s = (const float*)d_in[3];
  const float* att_d = (const float*)d_in[4];
  const float* bias  = (const float*)d_in[5];
  float* out = (float*)d_out;

  const int N = in_sizes[0] / F_IN;
  const int E = in_sizes[1] / 2;
  const int NB = (N + SCAN_CHUNK - 1) / SCAN_CHUNK;

  char* p = (char*)d_ws;
  unsigned short* wt = (unsigned short*)p; p += (size_t)F_IN * F_OUT * sizeof(unsigned short);
  float* h     = (float*)p;  p += (size_t)N * F_OUT * sizeof(float);
  float* a_src = (float*)p;  p += (size_t)N * sizeof(float);
  float* a_dst = (float*)p;  p += (size_t)N * sizeof(float);
  float* inv   = (float*)p;  p += (size_t)N * sizeof(float);
  int*   deg   = (int*)p;    p += (size_t)N * sizeof(int);
  int*   rowp  = (int*)p;    p += (size_t)(N + 1) * sizeof(int);
  int*   curs  = (int*)p;    p += (size_t)N * sizeof(int);
  int*   csum  = (int*)p;    p += (size_t)NB * sizeof(int);
  int*   coff  = (int*)p;    p += (size_t)NB * sizeof(int);
  int*   csr   = (int*)p;    p += (size_t)(E + N) * sizeof(int);
  float* ew    = (float*)p;  p += (size_t)(E + N) * sizeof(float);

  castW_kernel<<<(F_IN * F_OUT) / 256, 256, 0, stream>>>(W, wt);
  gemm_kernel<<<(N + 63) / 64, 256, 0, stream>>>(x, wt, att_s, att_d, h, a_src, a_dst, N);
  deg_init_kernel<<<(N + 255) / 256, 256, 0, stream>>>(deg, N);
  deg_count_kernel<<<(E + 255) / 256, 256, 0, stream>>>(ei, deg, E);
  scan_chunk_kernel<<<NB, 256, 0, stream>>>(deg, rowp, csum, N);
  scan_offsets_kernel<<<1, 64, 0, stream>>>(csum, coff, NB);
  scan_fixup_kernel<<<(N + 255) / 256, 256, 0, stream>>>(deg, rowp, curs, coff, N);
  scatter_kernel<<<(E + N + 255) / 256, 256, 0, stream>>>(ei, curs, a_src, a_dst, csr, ew, E, N);
  stats_kernel<<<((size_t)N * 16 + 255) / 256, 256, 0, stream>>>(rowp, ew, inv, N);
  aggregate_kernel<<<(N + 1) / 2, 256, 0, stream>>>(h, ew, inv, rowp, csr, bias, out, N);
}

// Round 5
// 241.423 us; speedup vs baseline: 2.0671x; 1.1938x over previous
//
#include <hip/hip_runtime.h>
#include <cstdint>
#include <cstddef>

#define F_IN 256
#define F_OUT 128
#define NEG_SLOPE 0.2f

typedef short short8 __attribute__((ext_vector_type(8)));
typedef float f32x4 __attribute__((ext_vector_type(4)));

__device__ __forceinline__ unsigned short f2bf_rne(float f) {
  unsigned u = __float_as_uint(f);
  u += 0x7FFFu + ((u >> 16) & 1u);   // round-to-nearest-even
  return (unsigned short)(u >> 16);
}

// ---------------- setup: cast+transpose W -> Wt[n][k] bf16, deg init ----------------
__global__ __launch_bounds__(256) void setup_kernel(const float* __restrict__ W,
                                                    unsigned short* __restrict__ Wt,
                                                    int* __restrict__ deg, int N) {
  int idx = blockIdx.x * 256 + threadIdx.x;
  if (idx < F_IN * F_OUT) {
    int n = idx & 127, k = idx >> 7;
    Wt[(size_t)n * F_IN + k] = f2bf_rne(W[(size_t)k * F_OUT + n]);
  }
  if (idx < N) deg[idx] = 1;  // self loop
}

// ---------------- GEMM: h = x @ W via bf16 MFMA + fused logits; h stored bf16 ----------------
#define WT_STRIDE 72   // 64 + 8 pad (bf16 elems)

__global__ __launch_bounds__(256, 4) void gemm_kernel(const float* __restrict__ x,
                                                      const unsigned short* __restrict__ Wt,
                                                      const float* __restrict__ att_src,
                                                      const float* __restrict__ att_dst,
                                                      unsigned short* __restrict__ hb,
                                                      float* __restrict__ a_src,
                                                      float* __restrict__ a_dst, int N) {
  __shared__ __attribute__((aligned(16))) unsigned short wt_l[128 * WT_STRIDE];
  const int tid  = threadIdx.x;
  const int lane = tid & 63;
  const int wv   = tid >> 6;        // wave = m-tile 0..3
  const int q    = lane >> 4;       // quad 0..3
  const int l16  = lane & 15;
  const int m0   = blockIdx.x * 64;
  const int m    = m0 + wv * 16 + l16;
  const int mc   = (m < N) ? m : (N - 1);

  f32x4 acc[8];
#pragma unroll
  for (int i = 0; i < 8; ++i) acc[i] = (f32x4)(0.f);

  const int srow  = tid >> 1;
  const int shalf = tid & 1;

#pragma unroll 1
  for (int t = 0; t < 4; ++t) {
    {
      const unsigned short* g = Wt + (size_t)srow * F_IN + t * 64 + shalf * 32;
      unsigned short* l = wt_l + srow * WT_STRIDE + shalf * 32;
#pragma unroll
      for (int j = 0; j < 4; ++j)
        *(uint4*)(l + j * 8) = *(const uint4*)(g + j * 8);
    }
    __syncthreads();

#pragma unroll
    for (int s = 0; s < 2; ++s) {
      const int kg = t * 64 + s * 32 + q * 8;
      f32x4 a0 = *(const f32x4*)(x + (size_t)mc * F_IN + kg);
      f32x4 a1 = *(const f32x4*)(x + (size_t)mc * F_IN + kg + 4);
      short8 av;
      av[0] = (short)f2bf_rne(a0[0]); av[1] = (short)f2bf_rne(a0[1]);
      av[2] = (short)f2bf_rne(a0[2]); av[3] = (short)f2bf_rne(a0[3]);
      av[4] = (short)f2bf_rne(a1[0]); av[5] = (short)f2bf_rne(a1[1]);
      av[6] = (short)f2bf_rne(a1[2]); av[7] = (short)f2bf_rne(a1[3]);
#pragma unroll
      for (int nt = 0; nt < 8; ++nt) {
        short8 bv = *(const short8*)(wt_l + (nt * 16 + l16) * WT_STRIDE + s * 32 + q * 8);
        acc[nt] = __builtin_amdgcn_mfma_f32_16x16x32_bf16(av, bv, acc[nt], 0, 0, 0);
      }
    }
    __syncthreads();
  }

  // ---- epilogue: bf16 h writes + fused logits (fp32-exact from accs) ----
  float as_c[8], ad_c[8];
#pragma unroll
  for (int nt = 0; nt < 8; ++nt) {
    as_c[nt] = att_src[nt * 16 + l16];
    ad_c[nt] = att_dst[nt * 16 + l16];
  }
  float ps[4] = {0.f, 0.f, 0.f, 0.f}, pd[4] = {0.f, 0.f, 0.f, 0.f};
#pragma unroll
  for (int nt = 0; nt < 8; ++nt)
#pragma unroll
    for (int r = 0; r < 4; ++r) {
      ps[r] += acc[nt][r] * as_c[nt];
      pd[r] += acc[nt][r] * ad_c[nt];
    }
#pragma unroll
  for (int r = 0; r < 4; ++r) {
    int gm = m0 + wv * 16 + q * 4 + r;
    if (gm < N) {
#pragma unroll
      for (int nt = 0; nt < 8; ++nt)
        hb[(size_t)gm * F_OUT + nt * 16 + l16] = f2bf_rne(acc[nt][r]);
    }
  }
#pragma unroll
  for (int r = 0; r < 4; ++r) {
#pragma unroll
    for (int off = 1; off <= 8; off <<= 1) {
      ps[r] += __shfl_xor(ps[r], off, 64);
      pd[r] += __shfl_xor(pd[r], off, 64);
    }
  }
  if (l16 == 0) {
#pragma unroll
    for (int r = 0; r < 4; ++r) {
      int gm = m0 + wv * 16 + q * 4 + r;
      if (gm < N) { a_src[gm] = ps[r]; a_dst[gm] = pd[r]; }
    }
  }
}

// ---------------- CSR build ----------------
__global__ void deg_count_kernel(const int* __restrict__ ei, int* __restrict__ deg, int E) {
  int e = blockIdx.x * blockDim.x + threadIdx.x;
  if (e < E) atomicAdd(&deg[ei[E + e]], 1);  // row 1 = dst
}

#define SCAN_CHUNK 2048  // 256 threads x 8 elements

__global__ __launch_bounds__(256) void scan_chunk_kernel(const int* __restrict__ deg,
                                                         int* __restrict__ rowptr,
                                                         int* __restrict__ chunksum, int N) {
  __shared__ int wsum[4];
  const int tid = threadIdx.x, lane = tid & 63, wid = tid >> 6;
  const int base = blockIdx.x * SCAN_CHUNK + tid * 8;
  int v[8];
  int s = 0;
#pragma unroll
  for (int q = 0; q < 8; ++q) {
    int i = base + q;
    v[q] = (i < N) ? deg[i] : 0;
    s += v[q];
  }
  int incl = s;
#pragma unroll
  for (int off = 1; off < 64; off <<= 1) {
    int t = __shfl_up(incl, off, 64);
    if (lane >= off) incl += t;
  }
  if (lane == 63) wsum[wid] = incl;
  __syncthreads();
  int woff = 0;
#pragma unroll
  for (int w = 0; w < 4; ++w)
    if (w < wid) woff += wsum[w];
  int run = woff + incl - s;
#pragma unroll
  for (int q = 0; q < 8; ++q) {
    run += v[q];
    int i = base + q;
    if (i < N) rowptr[i + 1] = run;
  }
  if (tid == 0) chunksum[blockIdx.x] = wsum[0] + wsum[1] + wsum[2] + wsum[3];
}

// fixup with inline chunk-prefix (chunksum is tiny, L2-broadcast)
__global__ void scan_fixup_kernel(const int* __restrict__ deg, int* __restrict__ rowptr,
                                  int* __restrict__ cursor, const int* __restrict__ chunksum,
                                  int N) {
  int i = blockIdx.x * blockDim.x + threadIdx.x;
  if (i == 0) rowptr[0] = 0;
  if (i < N) {
    int chunk = i / SCAN_CHUNK;
    int off = 0;
    for (int b = 0; b < chunk; ++b) off += chunksum[b];
    int r = rowptr[i + 1] + off;
    rowptr[i + 1] = r;
    cursor[i] = r - deg[i];
  }
}

// scatter + fused edge logit; packed (src, weight) record, one 8B store
__global__ void scatter_kernel(const int* __restrict__ ei, int* __restrict__ cursor,
                               const float* __restrict__ a_src, const float* __restrict__ a_dst,
                               int2* __restrict__ epack, int E, int N) {
  int idx = blockIdx.x * blockDim.x + threadIdx.x;
  if (idx >= E + N) return;
  int s, d;
  if (idx < E) { s = ei[idx]; d = ei[E + idx]; }
  else { s = d = idx - E; }
  float e = a_src[s] + a_dst[d];
  e = (e > 0.f) ? e : NEG_SLOPE * e;
  int p = atomicAdd(&cursor[d], 1);
  int2 rec; rec.x = s; rec.y = __float_as_int(e);
  epack[p] = rec;
}

// ---------------- softmax stats: 16 lanes per node, contiguous epack ----------------
__global__ __launch_bounds__(256) void stats_kernel(const int* __restrict__ rowptr,
                                                    int2* __restrict__ epack,
                                                    float* __restrict__ inv, int N) {
  int node = ((blockIdx.x * 256 + threadIdx.x) >> 4);
  int sub = threadIdx.x & 15;
  if (node >= N) return;
  int beg = rowptr[node], end = rowptr[node + 1];
  float m = -INFINITY;
  for (int j = beg + sub; j < end; j += 16) m = fmaxf(m, __int_as_float(epack[j].y));
#pragma unroll
  for (int off = 8; off >= 1; off >>= 1) m = fmaxf(m, __shfl_xor(m, off, 16));
  float s = 0.f;
  for (int j = beg + sub; j < end; j += 16) {
    float p = __expf(__int_as_float(epack[j].y) - m);
    epack[j].y = __float_as_int(p);
    s += p;
  }
#pragma unroll
  for (int off = 8; off >= 1; off >>= 1) s += __shfl_xor(s, off, 16);
  if (sub == 0) inv[node] = 1.f / (s + 1e-16f);
}

// ---------------- weighted aggregate: one wave per node, 2 features/lane (bf16x2) ----------------
__global__ __launch_bounds__(256) void aggregate_kernel(const unsigned short* __restrict__ hb,
                                                        const int2* __restrict__ epack,
                                                        const float* __restrict__ inv,
                                                        const int* __restrict__ rowptr,
                                                        const float* __restrict__ bias,
                                                        float* __restrict__ out, int N) {
  int node = (blockIdx.x * 256 + threadIdx.x) >> 6;
  if (node >= N) return;
  int lane = threadIdx.x & 63;
  int beg = rowptr[node], end = rowptr[node + 1];
  float acc0 = 0.f, acc1 = 0.f;
  int j = beg;
  for (; j + 4 <= end; j += 4) {
    int2 r0 = epack[j], r1 = epack[j + 1], r2 = epack[j + 2], r3 = epack[j + 3];
    unsigned u0 = *(const unsigned*)(hb + (size_t)r0.x * F_OUT + lane * 2);
    unsigned u1 = *(const unsigned*)(hb + (size_t)r1.x * F_OUT + lane * 2);
    unsigned u2 = *(const unsigned*)(hb + (size_t)r2.x * F_OUT + lane * 2);
    unsigned u3 = *(const unsigned*)(hb + (size_t)r3.x * F_OUT + lane * 2);
    float w0 = __int_as_float(r0.y), w1 = __int_as_float(r1.y);
    float w2 = __int_as_float(r2.y), w3 = __int_as_float(r3.y);
    acc0 += w0 * __uint_as_float(u0 << 16) + w1 * __uint_as_float(u1 << 16)
          + w2 * __uint_as_float(u2 << 16) + w3 * __uint_as_float(u3 << 16);
    acc1 += w0 * __uint_as_float(u0 & 0xFFFF0000u) + w1 * __uint_as_float(u1 & 0xFFFF0000u)
          + w2 * __uint_as_float(u2 & 0xFFFF0000u) + w3 * __uint_as_float(u3 & 0xFFFF0000u);
  }
  for (; j < end; ++j) {
    int2 r = epack[j];
    unsigned u = *(const unsigned*)(hb + (size_t)r.x * F_OUT + lane * 2);
    float w = __int_as_float(r.y);
    acc0 += w * __uint_as_float(u << 16);
    acc1 += w * __uint_as_float(u & 0xFFFF0000u);
  }
  float sc = inv[node];
  float2 o;
  o.x = acc0 * sc + bias[lane * 2];
  o.y = acc1 * sc + bias[lane * 2 + 1];
  *(float2*)&out[(size_t)node * F_OUT + lane * 2] = o;
}

// ---------------- launch ----------------
extern "C" void kernel_launch(void* const* d_in, const int* in_sizes, int n_in,
                              void* d_out, int out_size, void* d_ws, size_t ws_size,
                              hipStream_t stream) {
  const float* x     = (const float*)d_in[0];
  const int*   ei    = (const int*)d_in[1];
  const float* W     = (const float*)d_in[2];
  const float* att_s = (const float*)d_in[3];
  const float* att_d = (const float*)d_in[4];
  const float* bias  = (const float*)d_in[5];
  float* out = (float*)d_out;

  const int N = in_sizes[0] / F_IN;
  const int E = in_sizes[1] / 2;
  const int NB = (N + SCAN_CHUNK - 1) / SCAN_CHUNK;

  char* p = (char*)d_ws;
  unsigned short* wt = (unsigned short*)p; p += (size_t)F_IN * F_OUT * sizeof(unsigned short);
  unsigned short* hb = (unsigned short*)p; p += (size_t)N * F_OUT * sizeof(unsigned short);
  float* a_src = (float*)p;  p += (size_t)N * sizeof(float);
  float* a_dst = (float*)p;  p += (size_t)N * sizeof(float);
  float* inv   = (float*)p;  p += (size_t)N * sizeof(float);
  int*   deg   = (int*)p;    p += (size_t)N * sizeof(int);
  int*   rowp  = (int*)p;    p += (size_t)(N + 1) * sizeof(int);
  int*   curs  = (int*)p;    p += (size_t)N * sizeof(int);
  int*   csum  = (int*)p;    p += (size_t)NB * sizeof(int);
  p = (char*)(((uintptr_t)p + 15) & ~(uintptr_t)15);
  int2*  epack = (int2*)p;   p += (size_t)(E + N) * sizeof(int2);

  int setup_n = (F_IN * F_OUT > N) ? F_IN * F_OUT : N;
  setup_kernel<<<(setup_n + 255) / 256, 256, 0, stream>>>(W, wt, deg, N);
  gemm_kernel<<<(N + 63) / 64, 256, 0, stream>>>(x, wt, att_s, att_d, hb, a_src, a_dst, N);
  deg_count_kernel<<<(E + 255) / 256, 256, 0, stream>>>(ei, deg, E);
  scan_chunk_kernel<<<NB, 256, 0, stream>>>(deg, rowp, csum, N);
  scan_fixup_kernel<<<(N + 255) / 256, 256, 0, stream>>>(deg, rowp, curs, csum, N);
  scatter_kernel<<<(E + N + 255) / 256, 256, 0, stream>>>(ei, curs, a_src, a_dst, epack, E, N);
  stats_kernel<<<((size_t)N * 16 + 255) / 256, 256, 0, stream>>>(rowp, epack, inv, N);
  aggregate_kernel<<<((size_t)N * 64 + 255) / 256, 256, 0, stream>>>(hb, epack, inv, rowp, bias, out, N);
}

// Round 6
// 219.399 us; speedup vs baseline: 2.2746x; 1.1004x over previous
//
#include <hip/hip_runtime.h>
#include <cstdint>
#include <cstddef>

#define F_IN 256
#define F_OUT 128
#define NEG_SLOPE 0.2f

typedef short short8 __attribute__((ext_vector_type(8)));
typedef float f32x4 __attribute__((ext_vector_type(4)));

__device__ __forceinline__ unsigned short f2bf_rne(float f) {
  unsigned u = __float_as_uint(f);
  u += 0x7FFFu + ((u >> 16) & 1u);   // round-to-nearest-even
  return (unsigned short)(u >> 16);
}

// ---------------- setup: cast+transpose W -> Wt[n][k] bf16, deg=0 ----------------
__global__ __launch_bounds__(256) void setup_kernel(const float* __restrict__ W,
                                                    unsigned short* __restrict__ Wt,
                                                    int* __restrict__ deg, int N) {
  int idx = blockIdx.x * 256 + threadIdx.x;
  if (idx < F_IN * F_OUT) {
    int n = idx & 127, k = idx >> 7;
    Wt[(size_t)n * F_IN + k] = f2bf_rne(W[(size_t)k * F_OUT + n]);
  }
  if (idx < N) deg[idx] = 0;  // counts real edges only; self loop added in scan
}

// ---------------- GEMM: h = x @ W via bf16 MFMA + fused logits; h stored bf16 ----------------
#define WT_STRIDE 72   // 64 + 8 pad (bf16 elems)

__global__ __launch_bounds__(256, 4) void gemm_kernel(const float* __restrict__ x,
                                                      const unsigned short* __restrict__ Wt,
                                                      const float* __restrict__ att_src,
                                                      const float* __restrict__ att_dst,
                                                      unsigned short* __restrict__ hb,
                                                      float* __restrict__ a_src,
                                                      float* __restrict__ a_dst, int N) {
  __shared__ __attribute__((aligned(16))) unsigned short wt_l[128 * WT_STRIDE];
  const int tid  = threadIdx.x;
  const int lane = tid & 63;
  const int wv   = tid >> 6;        // wave = m-tile 0..3
  const int q    = lane >> 4;       // quad 0..3
  const int l16  = lane & 15;
  const int m0   = blockIdx.x * 64;
  const int m    = m0 + wv * 16 + l16;
  const int mc   = (m < N) ? m : (N - 1);

  f32x4 acc[8];
#pragma unroll
  for (int i = 0; i < 8; ++i) acc[i] = (f32x4)(0.f);

  const int srow  = tid >> 1;
  const int shalf = tid & 1;

#pragma unroll 1
  for (int t = 0; t < 4; ++t) {
    {
      const unsigned short* g = Wt + (size_t)srow * F_IN + t * 64 + shalf * 32;
      unsigned short* l = wt_l + srow * WT_STRIDE + shalf * 32;
#pragma unroll
      for (int j = 0; j < 4; ++j)
        *(uint4*)(l + j * 8) = *(const uint4*)(g + j * 8);
    }
    __syncthreads();

#pragma unroll
    for (int s = 0; s < 2; ++s) {
      const int kg = t * 64 + s * 32 + q * 8;
      f32x4 a0 = *(const f32x4*)(x + (size_t)mc * F_IN + kg);
      f32x4 a1 = *(const f32x4*)(x + (size_t)mc * F_IN + kg + 4);
      short8 av;
      av[0] = (short)f2bf_rne(a0[0]); av[1] = (short)f2bf_rne(a0[1]);
      av[2] = (short)f2bf_rne(a0[2]); av[3] = (short)f2bf_rne(a0[3]);
      av[4] = (short)f2bf_rne(a1[0]); av[5] = (short)f2bf_rne(a1[1]);
      av[6] = (short)f2bf_rne(a1[2]); av[7] = (short)f2bf_rne(a1[3]);
#pragma unroll
      for (int nt = 0; nt < 8; ++nt) {
        short8 bv = *(const short8*)(wt_l + (nt * 16 + l16) * WT_STRIDE + s * 32 + q * 8);
        acc[nt] = __builtin_amdgcn_mfma_f32_16x16x32_bf16(av, bv, acc[nt], 0, 0, 0);
      }
    }
    __syncthreads();
  }

  // ---- epilogue: bf16 h writes + fused logits (fp32-exact from accs) ----
  float as_c[8], ad_c[8];
#pragma unroll
  for (int nt = 0; nt < 8; ++nt) {
    as_c[nt] = att_src[nt * 16 + l16];
    ad_c[nt] = att_dst[nt * 16 + l16];
  }
  float ps[4] = {0.f, 0.f, 0.f, 0.f}, pd[4] = {0.f, 0.f, 0.f, 0.f};
#pragma unroll
  for (int nt = 0; nt < 8; ++nt)
#pragma unroll
    for (int r = 0; r < 4; ++r) {
      ps[r] += acc[nt][r] * as_c[nt];
      pd[r] += acc[nt][r] * ad_c[nt];
    }
#pragma unroll
  for (int r = 0; r < 4; ++r) {
    int gm = m0 + wv * 16 + q * 4 + r;
    if (gm < N) {
#pragma unroll
      for (int nt = 0; nt < 8; ++nt)
        hb[(size_t)gm * F_OUT + nt * 16 + l16] = f2bf_rne(acc[nt][r]);
    }
  }
#pragma unroll
  for (int r = 0; r < 4; ++r) {
#pragma unroll
    for (int off = 1; off <= 8; off <<= 1) {
      ps[r] += __shfl_xor(ps[r], off, 64);
      pd[r] += __shfl_xor(pd[r], off, 64);
    }
  }
  if (l16 == 0) {
#pragma unroll
    for (int r = 0; r < 4; ++r) {
      int gm = m0 + wv * 16 + q * 4 + r;
      if (gm < N) { a_src[gm] = ps[r]; a_dst[gm] = pd[r]; }
    }
  }
}

// ---------------- degree count + slot rank (coalesced rank write) ----------------
__global__ void deg_rank_kernel(const int* __restrict__ ei, int* __restrict__ deg,
                                int* __restrict__ rank, int E) {
  int e = blockIdx.x * blockDim.x + threadIdx.x;
  if (e < E) rank[e] = atomicAdd(&deg[ei[E + e]], 1);
}

#define SCAN_CHUNK 2048  // 256 threads x 8 elements

__global__ __launch_bounds__(256) void scan_chunk_kernel(const int* __restrict__ deg,
                                                         int* __restrict__ rowptr,
                                                         int* __restrict__ chunksum, int N) {
  __shared__ int wsum[4];
  const int tid = threadIdx.x, lane = tid & 63, wid = tid >> 6;
  const int base = blockIdx.x * SCAN_CHUNK + tid * 8;
  int v[8];
  int s = 0;
#pragma unroll
  for (int q = 0; q < 8; ++q) {
    int i = base + q;
    v[q] = (i < N) ? (deg[i] + 1) : 0;   // +1 = self loop slot
    s += v[q];
  }
  int incl = s;
#pragma unroll
  for (int off = 1; off < 64; off <<= 1) {
    int t = __shfl_up(incl, off, 64);
    if (lane >= off) incl += t;
  }
  if (lane == 63) wsum[wid] = incl;
  __syncthreads();
  int woff = 0;
#pragma unroll
  for (int w = 0; w < 4; ++w)
    if (w < wid) woff += wsum[w];
  int run = woff + incl - s;
#pragma unroll
  for (int q = 0; q < 8; ++q) {
    run += v[q];
    int i = base + q;
    if (i < N) rowptr[i + 1] = run;
  }
  if (tid == 0) chunksum[blockIdx.x] = wsum[0] + wsum[1] + wsum[2] + wsum[3];
}

// fixup with inline chunk-prefix (chunksum is tiny, L2-broadcast)
__global__ void scan_fixup_kernel(int* __restrict__ rowptr, const int* __restrict__ chunksum,
                                  int N) {
  int i = blockIdx.x * blockDim.x + threadIdx.x;
  if (i == 0) rowptr[0] = 0;
  if (i < N) {
    int chunk = i / SCAN_CHUNK;
    int off = 0;
    for (int b = 0; b < chunk; ++b) off += chunksum[b];
    rowptr[i + 1] += off;
  }
}

// atomic-free scatter: position known, fire-and-forget 4B store
__global__ void scatter_kernel(const int* __restrict__ ei, const int* __restrict__ rowptr,
                               const int* __restrict__ rank, int* __restrict__ csr_src,
                               int E, int N) {
  int idx = blockIdx.x * blockDim.x + threadIdx.x;
  if (idx < E) {
    int d = ei[E + idx];
    csr_src[rowptr[d] + rank[idx]] = ei[idx];
  } else if (idx < E + N) {
    int i = idx - E;
    csr_src[rowptr[i + 1] - 1] = i;   // self loop in last slot
  }
}

// ---------------- softmax stats: 16 lanes/node; gathers L2-resident logits ----------------
__global__ __launch_bounds__(256) void stats_kernel(const int* __restrict__ rowptr,
                                                    const int* __restrict__ csr_src,
                                                    const float* __restrict__ a_src,
                                                    const float* __restrict__ a_dst,
                                                    float* __restrict__ ew,
                                                    float* __restrict__ inv, int N) {
  int node = ((blockIdx.x * 256 + threadIdx.x) >> 4);
  int sub = threadIdx.x & 15;
  if (node >= N) return;
  int beg = rowptr[node], end = rowptr[node + 1];
  float ad = a_dst[node];
  float m = -INFINITY;
  for (int j = beg + sub; j < end; j += 16) {
    float e = a_src[csr_src[j]] + ad;
    e = (e > 0.f) ? e : NEG_SLOPE * e;
    ew[j] = e;
    m = fmaxf(m, e);
  }
#pragma unroll
  for (int off = 8; off >= 1; off >>= 1) m = fmaxf(m, __shfl_xor(m, off, 16));
  float s = 0.f;
  for (int j = beg + sub; j < end; j += 16) {
    float p = __expf(ew[j] - m);
    ew[j] = p;
    s += p;
  }
#pragma unroll
  for (int off = 8; off >= 1; off >>= 1) s += __shfl_xor(s, off, 16);
  if (sub == 0) inv[node] = 1.f / (s + 1e-16f);
}

// ---------------- weighted aggregate: one wave per node, 2 features/lane (bf16x2) ----------------
__global__ __launch_bounds__(256) void aggregate_kernel(const unsigned short* __restrict__ hb,
                                                        const int* __restrict__ csr_src,
                                                        const float* __restrict__ ew,
                                                        const float* __restrict__ inv,
                                                        const int* __restrict__ rowptr,
                                                        const float* __restrict__ bias,
                                                        float* __restrict__ out, int N) {
  int node = (blockIdx.x * 256 + threadIdx.x) >> 6;
  if (node >= N) return;
  int lane = threadIdx.x & 63;
  int beg = rowptr[node], end = rowptr[node + 1];
  float acc0 = 0.f, acc1 = 0.f;
  int j = beg;
  for (; j + 4 <= end; j += 4) {
    int s0 = csr_src[j], s1 = csr_src[j + 1], s2 = csr_src[j + 2], s3 = csr_src[j + 3];
    float w0 = ew[j], w1 = ew[j + 1], w2 = ew[j + 2], w3 = ew[j + 3];
    unsigned u0 = *(const unsigned*)(hb + (size_t)s0 * F_OUT + lane * 2);
    unsigned u1 = *(const unsigned*)(hb + (size_t)s1 * F_OUT + lane * 2);
    unsigned u2 = *(const unsigned*)(hb + (size_t)s2 * F_OUT + lane * 2);
    unsigned u3 = *(const unsigned*)(hb + (size_t)s3 * F_OUT + lane * 2);
    acc0 += w0 * __uint_as_float(u0 << 16) + w1 * __uint_as_float(u1 << 16)
          + w2 * __uint_as_float(u2 << 16) + w3 * __uint_as_float(u3 << 16);
    acc1 += w0 * __uint_as_float(u0 & 0xFFFF0000u) + w1 * __uint_as_float(u1 & 0xFFFF0000u)
          + w2 * __uint_as_float(u2 & 0xFFFF0000u) + w3 * __uint_as_float(u3 & 0xFFFF0000u);
  }
  for (; j < end; ++j) {
    int s = csr_src[j];
    float w = ew[j];
    unsigned u = *(const unsigned*)(hb + (size_t)s * F_OUT + lane * 2);
    acc0 += w * __uint_as_float(u << 16);
    acc1 += w * __uint_as_float(u & 0xFFFF0000u);
  }
  float sc = inv[node];
  float2 o;
  o.x = acc0 * sc + bias[lane * 2];
  o.y = acc1 * sc + bias[lane * 2 + 1];
  *(float2*)&out[(size_t)node * F_OUT + lane * 2] = o;
}

// ---------------- launch ----------------
extern "C" void kernel_launch(void* const* d_in, const int* in_sizes, int n_in,
                              void* d_out, int out_size, void* d_ws, size_t ws_size,
                              hipStream_t stream) {
  const float* x     = (const float*)d_in[0];
  const int*   ei    = (const int*)d_in[1];
  const float* W     = (const float*)d_in[2];
  const float* att_s = (const float*)d_in[3];
  const float* att_d = (const float*)d_in[4];
  const float* bias  = (const float*)d_in[5];
  float* out = (float*)d_out;

  const int N = in_sizes[0] / F_IN;
  const int E = in_sizes[1] / 2;
  const int NB = (N + SCAN_CHUNK - 1) / SCAN_CHUNK;

  char* p = (char*)d_ws;
  unsigned short* wt = (unsigned short*)p; p += (size_t)F_IN * F_OUT * sizeof(unsigned short);
  unsigned short* hb = (unsigned short*)p; p += (size_t)N * F_OUT * sizeof(unsigned short);
  float* a_src = (float*)p;  p += (size_t)N * sizeof(float);
  float* a_dst = (float*)p;  p += (size_t)N * sizeof(float);
  float* inv   = (float*)p;  p += (size_t)N * sizeof(float);
  int*   deg   = (int*)p;    p += (size_t)N * sizeof(int);
  int*   rowp  = (int*)p;    p += (size_t)(N + 1) * sizeof(int);
  int*   csum  = (int*)p;    p += (size_t)NB * sizeof(int);
  int*   rank  = (int*)p;    p += (size_t)E * sizeof(int);
  int*   csr   = (int*)p;    p += (size_t)(E + N) * sizeof(int);
  float* ew    = (float*)p;  p += (size_t)(E + N) * sizeof(float);

  int setup_n = (F_IN * F_OUT > N) ? F_IN * F_OUT : N;
  setup_kernel<<<(setup_n + 255) / 256, 256, 0, stream>>>(W, wt, deg, N);
  gemm_kernel<<<(N + 63) / 64, 256, 0, stream>>>(x, wt, att_s, att_d, hb, a_src, a_dst, N);
  deg_rank_kernel<<<(E + 255) / 256, 256, 0, stream>>>(ei, deg, rank, E);
  scan_chunk_kernel<<<NB, 256, 0, stream>>>(deg, rowp, csum, N);
  scan_fixup_kernel<<<(N + 255) / 256, 256, 0, stream>>>(rowp, csum, N);
  scatter_kernel<<<(E + N + 255) / 256, 256, 0, stream>>>(ei, rowp, rank, csr, E, N);
  stats_kernel<<<((size_t)N * 16 + 255) / 256, 256, 0, stream>>>(rowp, csr, a_src, a_dst, ew, inv, N);
  aggregate_kernel<<<((size_t)N * 64 + 255) / 256, 256, 0, stream>>>(hb, csr, ew, inv, rowp, bias, out, N);
}

// Round 7
// 217.009 us; speedup vs baseline: 2.2996x; 1.0110x over previous
//
#include <hip/hip_runtime.h>
#include <cstdint>
#include <cstddef>

#define F_IN 256
#define F_OUT 128
#define NEG_SLOPE 0.2f

typedef short short8 __attribute__((ext_vector_type(8)));
typedef float f32x4 __attribute__((ext_vector_type(4)));

__device__ __forceinline__ unsigned short f2bf_rne(float f) {
  unsigned u = __float_as_uint(f);
  u += 0x7FFFu + ((u >> 16) & 1u);   // round-to-nearest-even
  return (unsigned short)(u >> 16);
}

__device__ __forceinline__ float bf_lo(unsigned u) { return __uint_as_float(u << 16); }
__device__ __forceinline__ float bf_hi(unsigned u) { return __uint_as_float(u & 0xFFFF0000u); }

// ---------------- setup: cast+transpose W -> Wt[n][k] bf16, deg=0 ----------------
__global__ __launch_bounds__(256) void setup_kernel(const float* __restrict__ W,
                                                    unsigned short* __restrict__ Wt,
                                                    int* __restrict__ deg, int N) {
  int idx = blockIdx.x * 256 + threadIdx.x;
  if (idx < F_IN * F_OUT) {
    int n = idx & 127, k = idx >> 7;
    Wt[(size_t)n * F_IN + k] = f2bf_rne(W[(size_t)k * F_OUT + n]);
  }
  if (idx < N) deg[idx] = 0;  // counts real edges only
}

// ---------------- GEMM: h = x @ W via bf16 MFMA + fused logits; h stored bf16 ----------------
#define WT_STRIDE 72   // 64 + 8 pad (bf16 elems)

__global__ __launch_bounds__(256, 4) void gemm_kernel(const float* __restrict__ x,
                                                      const unsigned short* __restrict__ Wt,
                                                      const float* __restrict__ att_src,
                                                      const float* __restrict__ att_dst,
                                                      unsigned short* __restrict__ hb,
                                                      float* __restrict__ a_src,
                                                      float* __restrict__ a_dst, int N) {
  __shared__ __attribute__((aligned(16))) unsigned short wt_l[128 * WT_STRIDE];
  const int tid  = threadIdx.x;
  const int lane = tid & 63;
  const int wv   = tid >> 6;
  const int q    = lane >> 4;
  const int l16  = lane & 15;
  const int m0   = blockIdx.x * 64;
  const int m    = m0 + wv * 16 + l16;
  const int mc   = (m < N) ? m : (N - 1);

  f32x4 acc[8];
#pragma unroll
  for (int i = 0; i < 8; ++i) acc[i] = (f32x4)(0.f);

  const int srow  = tid >> 1;
  const int shalf = tid & 1;

#pragma unroll 1
  for (int t = 0; t < 4; ++t) {
    {
      const unsigned short* g = Wt + (size_t)srow * F_IN + t * 64 + shalf * 32;
      unsigned short* l = wt_l + srow * WT_STRIDE + shalf * 32;
#pragma unroll
      for (int j = 0; j < 4; ++j)
        *(uint4*)(l + j * 8) = *(const uint4*)(g + j * 8);
    }
    __syncthreads();

#pragma unroll
    for (int s = 0; s < 2; ++s) {
      const int kg = t * 64 + s * 32 + q * 8;
      f32x4 a0 = *(const f32x4*)(x + (size_t)mc * F_IN + kg);
      f32x4 a1 = *(const f32x4*)(x + (size_t)mc * F_IN + kg + 4);
      short8 av;
      av[0] = (short)f2bf_rne(a0[0]); av[1] = (short)f2bf_rne(a0[1]);
      av[2] = (short)f2bf_rne(a0[2]); av[3] = (short)f2bf_rne(a0[3]);
      av[4] = (short)f2bf_rne(a1[0]); av[5] = (short)f2bf_rne(a1[1]);
      av[6] = (short)f2bf_rne(a1[2]); av[7] = (short)f2bf_rne(a1[3]);
#pragma unroll
      for (int nt = 0; nt < 8; ++nt) {
        short8 bv = *(const short8*)(wt_l + (nt * 16 + l16) * WT_STRIDE + s * 32 + q * 8);
        acc[nt] = __builtin_amdgcn_mfma_f32_16x16x32_bf16(av, bv, acc[nt], 0, 0, 0);
      }
    }
    __syncthreads();
  }

  float as_c[8], ad_c[8];
#pragma unroll
  for (int nt = 0; nt < 8; ++nt) {
    as_c[nt] = att_src[nt * 16 + l16];
    ad_c[nt] = att_dst[nt * 16 + l16];
  }
  float ps[4] = {0.f, 0.f, 0.f, 0.f}, pd[4] = {0.f, 0.f, 0.f, 0.f};
#pragma unroll
  for (int nt = 0; nt < 8; ++nt)
#pragma unroll
    for (int r = 0; r < 4; ++r) {
      ps[r] += acc[nt][r] * as_c[nt];
      pd[r] += acc[nt][r] * ad_c[nt];
    }
#pragma unroll
  for (int r = 0; r < 4; ++r) {
    int gm = m0 + wv * 16 + q * 4 + r;
    if (gm < N) {
#pragma unroll
      for (int nt = 0; nt < 8; ++nt)
        hb[(size_t)gm * F_OUT + nt * 16 + l16] = f2bf_rne(acc[nt][r]);
    }
  }
#pragma unroll
  for (int r = 0; r < 4; ++r) {
#pragma unroll
    for (int off = 1; off <= 8; off <<= 1) {
      ps[r] += __shfl_xor(ps[r], off, 64);
      pd[r] += __shfl_xor(pd[r], off, 64);
    }
  }
  if (l16 == 0) {
#pragma unroll
    for (int r = 0; r < 4; ++r) {
      int gm = m0 + wv * 16 + q * 4 + r;
      if (gm < N) { a_src[gm] = ps[r]; a_dst[gm] = pd[r]; }
    }
  }
}

// ---------------- degree count + slot rank (coalesced rank write) ----------------
__global__ void deg_rank_kernel(const int* __restrict__ ei, int* __restrict__ deg,
                                int* __restrict__ rank, int E) {
  int e = blockIdx.x * blockDim.x + threadIdx.x;
  if (e < E) rank[e] = atomicAdd(&deg[ei[E + e]], 1);
}

#define SCAN_CHUNK 2048  // 256 threads x 8 elements

// CSR rows padded to multiple of 4 slots -> every row start is 16B-aligned
__global__ __launch_bounds__(256) void scan_chunk_kernel(const int* __restrict__ deg,
                                                         int* __restrict__ rowptr,
                                                         int* __restrict__ chunksum, int N) {
  __shared__ int wsum[4];
  const int tid = threadIdx.x, lane = tid & 63, wid = tid >> 6;
  const int base = blockIdx.x * SCAN_CHUNK + tid * 8;
  int v[8];
  int s = 0;
#pragma unroll
  for (int q = 0; q < 8; ++q) {
    int i = base + q;
    v[q] = (i < N) ? ((deg[i] + 1 + 3) & ~3) : 0;   // deg real edges + self loop, pad to x4
    s += v[q];
  }
  int incl = s;
#pragma unroll
  for (int off = 1; off < 64; off <<= 1) {
    int t = __shfl_up(incl, off, 64);
    if (lane >= off) incl += t;
  }
  if (lane == 63) wsum[wid] = incl;
  __syncthreads();
  int woff = 0;
#pragma unroll
  for (int w = 0; w < 4; ++w)
    if (w < wid) woff += wsum[w];
  int run = woff + incl - s;
#pragma unroll
  for (int q = 0; q < 8; ++q) {
    run += v[q];
    int i = base + q;
    if (i < N) rowptr[i + 1] = run;
  }
  if (tid == 0) chunksum[blockIdx.x] = wsum[0] + wsum[1] + wsum[2] + wsum[3];
}

__global__ void scan_fixup_kernel(int* __restrict__ rowptr, const int* __restrict__ chunksum,
                                  int N) {
  int i = blockIdx.x * blockDim.x + threadIdx.x;
  if (i == 0) rowptr[0] = 0;
  if (i < N) {
    int chunk = i / SCAN_CHUNK;
    int off = 0;
    for (int b = 0; b < chunk; ++b) off += chunksum[b];
    rowptr[i + 1] += off;
  }
}

// atomic-free scatter; self loop at slot beg+deg (real entries contiguous)
__global__ void scatter_kernel(const int* __restrict__ ei, const int* __restrict__ rowptr,
                               const int* __restrict__ rank, const int* __restrict__ deg,
                               int* __restrict__ csr_src, int E, int N) {
  int idx = blockIdx.x * blockDim.x + threadIdx.x;
  if (idx < E) {
    int d = ei[E + idx];
    csr_src[rowptr[d] + rank[idx]] = ei[idx];
  } else if (idx < E + N) {
    int i = idx - E;
    csr_src[rowptr[i] + deg[i]] = i;
  }
}

// ---------------- softmax stats: 16 lanes/node ----------------
__global__ __launch_bounds__(256) void stats_kernel(const int* __restrict__ rowptr,
                                                    const int* __restrict__ deg,
                                                    const int* __restrict__ csr_src,
                                                    const float* __restrict__ a_src,
                                                    const float* __restrict__ a_dst,
                                                    float* __restrict__ ew,
                                                    float* __restrict__ inv, int N) {
  int node = ((blockIdx.x * 256 + threadIdx.x) >> 4);
  int sub = threadIdx.x & 15;
  if (node >= N) return;
  int beg = rowptr[node], end = beg + deg[node] + 1;
  float ad = a_dst[node];
  float m = -INFINITY;
  for (int j = beg + sub; j < end; j += 16) {
    float e = a_src[csr_src[j]] + ad;
    e = (e > 0.f) ? e : NEG_SLOPE * e;
    ew[j] = e;
    m = fmaxf(m, e);
  }
#pragma unroll
  for (int off = 8; off >= 1; off >>= 1) m = fmaxf(m, __shfl_xor(m, off, 16));
  float s = 0.f;
  for (int j = beg + sub; j < end; j += 16) {
    float p = __expf(ew[j] - m);
    ew[j] = p;
    s += p;
  }
#pragma unroll
  for (int off = 8; off >= 1; off >>= 1) s += __shfl_xor(s, off, 16);
  if (sub == 0) inv[node] = 1.f / (s + 1e-16f);
}

// ---------------- weighted aggregate: wave/node, 2 edges per gather instruction ----------------
__global__ __launch_bounds__(256) void aggregate_kernel(const unsigned short* __restrict__ hb,
                                                        const int* __restrict__ csr_src,
                                                        const float* __restrict__ ew,
                                                        const float* __restrict__ inv,
                                                        const int* __restrict__ rowptr,
                                                        const int* __restrict__ deg,
                                                        const float* __restrict__ bias,
                                                        float* __restrict__ out, int N) {
  int node = (blockIdx.x * 256 + threadIdx.x) >> 6;
  if (node >= N) return;
  int lane = threadIdx.x & 63;
  int half = lane >> 5;        // which of 2 concurrent edges this lane serves
  int l32  = lane & 31;        // feature group: features l32*4 .. l32*4+3
  int beg = rowptr[node];      // 16B-aligned (padded CSR)
  int end = beg + deg[node] + 1;

  f32x4 acc = (f32x4)(0.f);
  int j = beg;
  for (; j + 8 <= end; j += 8) {
    int4   c0 = *(const int4*)(csr_src + j);
    int4   c1 = *(const int4*)(csr_src + j + 4);
    float4 w0 = *(const float4*)(ew + j);
    float4 w1 = *(const float4*)(ew + j + 4);
    int   cs[8] = {c0.x, c0.y, c0.z, c0.w, c1.x, c1.y, c1.z, c1.w};
    float wv[8] = {w0.x, w0.y, w0.z, w0.w, w1.x, w1.y, w1.z, w1.w};
#pragma unroll
    for (int u = 0; u < 4; ++u) {
      int   s = cs[2 * u + half];
      float w = wv[2 * u + half];
      uint2 hv = *(const uint2*)(hb + (size_t)s * F_OUT + l32 * 4);
      acc[0] += w * bf_lo(hv.x);
      acc[1] += w * bf_hi(hv.x);
      acc[2] += w * bf_lo(hv.y);
      acc[3] += w * bf_hi(hv.y);
    }
  }
  for (; j + 2 <= end; j += 2) {
    int   s = csr_src[j + half];
    float w = ew[j + half];
    uint2 hv = *(const uint2*)(hb + (size_t)s * F_OUT + l32 * 4);
    acc[0] += w * bf_lo(hv.x);
    acc[1] += w * bf_hi(hv.x);
    acc[2] += w * bf_lo(hv.y);
    acc[3] += w * bf_hi(hv.y);
  }
  if (j < end && half == 0) {
    int   s = csr_src[j];
    float w = ew[j];
    uint2 hv = *(const uint2*)(hb + (size_t)s * F_OUT + l32 * 4);
    acc[0] += w * bf_lo(hv.x);
    acc[1] += w * bf_hi(hv.x);
    acc[2] += w * bf_lo(hv.y);
    acc[3] += w * bf_hi(hv.y);
  }
  // combine the two edge-halves
#pragma unroll
  for (int k = 0; k < 4; ++k) acc[k] += __shfl_xor(acc[k], 32, 64);

  if (half == 0) {
    float sc = inv[node];
    float4 b = *(const float4*)(bias + l32 * 4);
    float4 o;
    o.x = acc[0] * sc + b.x;
    o.y = acc[1] * sc + b.y;
    o.z = acc[2] * sc + b.z;
    o.w = acc[3] * sc + b.w;
    *(float4*)&out[(size_t)node * F_OUT + l32 * 4] = o;
  }
}

// ---------------- launch ----------------
extern "C" void kernel_launch(void* const* d_in, const int* in_sizes, int n_in,
                              void* d_out, int out_size, void* d_ws, size_t ws_size,
                              hipStream_t stream) {
  const float* x     = (const float*)d_in[0];
  const int*   ei    = (const int*)d_in[1];
  const float* W     = (const float*)d_in[2];
  const float* att_s = (const float*)d_in[3];
  const float* att_d = (const float*)d_in[4];
  const float* bias  = (const float*)d_in[5];
  float* out = (float*)d_out;

  const int N = in_sizes[0] / F_IN;
  const int E = in_sizes[1] / 2;
  const int NB = (N + SCAN_CHUNK - 1) / SCAN_CHUNK;
  const size_t CSR_CAP = (size_t)E + 4 * (size_t)N + 8;  // padded rows worst case

  char* p = (char*)d_ws;
  unsigned short* wt = (unsigned short*)p; p += (size_t)F_IN * F_OUT * sizeof(unsigned short);
  unsigned short* hb = (unsigned short*)p; p += (size_t)N * F_OUT * sizeof(unsigned short);
  float* a_src = (float*)p;  p += (size_t)N * sizeof(float);
  float* a_dst = (float*)p;  p += (size_t)N * sizeof(float);
  float* inv   = (float*)p;  p += (size_t)N * sizeof(float);
  int*   deg   = (int*)p;    p += (size_t)N * sizeof(int);
  int*   rowp  = (int*)p;    p += (size_t)(N + 1) * sizeof(int);
  int*   csum  = (int*)p;    p += (size_t)NB * sizeof(int);
  int*   rank  = (int*)p;    p += (size_t)E * sizeof(int);
  p = (char*)(((uintptr_t)p + 15) & ~(uintptr_t)15);
  int*   csr   = (int*)p;    p += CSR_CAP * sizeof(int);
  p = (char*)(((uintptr_t)p + 15) & ~(uintptr_t)15);
  float* ew    = (float*)p;  p += CSR_CAP * sizeof(float);

  int setup_n = (F_IN * F_OUT > N) ? F_IN * F_OUT : N;
  setup_kernel<<<(setup_n + 255) / 256, 256, 0, stream>>>(W, wt, deg, N);
  gemm_kernel<<<(N + 63) / 64, 256, 0, stream>>>(x, wt, att_s, att_d, hb, a_src, a_dst, N);
  deg_rank_kernel<<<(E + 255) / 256, 256, 0, stream>>>(ei, deg, rank, E);
  scan_chunk_kernel<<<NB, 256, 0, stream>>>(deg, rowp, csum, N);
  scan_fixup_kernel<<<(N + 255) / 256, 256, 0, stream>>>(rowp, csum, N);
  scatter_kernel<<<(E + N + 255) / 256, 256, 0, stream>>>(ei, rowp, rank, deg, csr, E, N);
  stats_kernel<<<((size_t)N * 16 + 255) / 256, 256, 0, stream>>>(rowp, deg, csr, a_src, a_dst, ew, inv, N);
  aggregate_kernel<<<((size_t)N * 64 + 255) / 256, 256, 0, stream>>>(hb, csr, ew, inv, rowp, deg, bias, out, N);
}